// Round 4
// baseline (1513.263 us; speedup 1.0000x reference)
//
#include <hip/hip_runtime.h>
#include <hip/hip_bf16.h>

#define DIM 64
#define BKN 256              // nodes per bucket
#define BKSH 8               // log2(BKN)
#define MAXBK 400            // supports N <= 102400
#define SLOTS 12             // staged records per bucket (flush 8, keep <=4)

__device__ inline float fast_tanh(float x) {
    float e = __expf(2.0f * x);
    return 1.0f - 2.0f / (e + 1.0f);
}

// ---------- gates: per-node dot products + bf16 copy of h ----------
__global__ void fa_node_gates(const float* __restrict__ h,
                              const float* __restrict__ gate_W,
                              float* __restrict__ gd,
                              float* __restrict__ gs,
                              __hip_bfloat16* __restrict__ hb,   // may be null
                              int N) {
    int gid  = blockIdx.x * blockDim.x + threadIdx.x;
    int node = gid >> 6;
    int lane = threadIdx.x & 63;
    if (node >= N) return;
    float x = h[(size_t)node * DIM + lane];
    if (hb) hb[(size_t)node * DIM + lane] = __float2bfloat16(x);
    float a = x * gate_W[lane];
    float b = x * gate_W[DIM + lane];
    #pragma unroll
    for (int off = 32; off >= 1; off >>= 1) {
        a += __shfl_xor(a, off, 64);
        b += __shfl_xor(b, off, 64);
    }
    if (lane == 0) {
        gd[node] = a;
        gs[node] = b;
    }
}

// ---------- bucket histogram (LDS-privatized) ----------
__global__ void fa_hist_bk(const int* __restrict__ edst, int* __restrict__ cntbk, int E) {
    __shared__ int lh[MAXBK];
    for (int i = threadIdx.x; i < MAXBK; i += blockDim.x) lh[i] = 0;
    __syncthreads();
    int stride = gridDim.x * blockDim.x;
    for (int i = blockIdx.x * blockDim.x + threadIdx.x; i < E; i += stride)
        atomicAdd(&lh[edst[i] >> BKSH], 1);
    __syncthreads();
    for (int i = threadIdx.x; i < MAXBK; i += blockDim.x)
        if (lh[i]) atomicAdd(&cntbk[i], lh[i]);
}

// ---------- bucket scan: 64B-aligned exclusive offsets + cursors ----------
__global__ void fa_scan_bk(const int* __restrict__ cntbk, int* __restrict__ offbk,
                           int* __restrict__ gcur, int nbk) {
    __shared__ int sc[512];
    int tid = threadIdx.x;
    int v = (tid < nbk) ? ((cntbk[tid] + 7) & ~7) : 0;   // align regions to 8 recs = 64B
    sc[tid] = v;
    __syncthreads();
    for (int dd = 1; dd < 512; dd <<= 1) {
        int t = (tid >= dd) ? sc[tid - dd] : 0;
        __syncthreads();
        sc[tid] += t;
        __syncthreads();
    }
    if (tid < nbk) {
        int off = sc[tid] - v;
        offbk[tid] = off;
        gcur[tid]  = off;
    }
}

// ---------- scatter with LDS write-combining (full 64B flushes) ----------
__global__ void fa_scatter_bk(const float* __restrict__ gd, const float* __restrict__ gs,
                              const float* __restrict__ d,
                              const int* __restrict__ esrc, const int* __restrict__ edst,
                              const float* __restrict__ gate_b,
                              int* __restrict__ gcur, int2* __restrict__ pairs,
                              int E, int nbk) {
    __shared__ int2 stage[MAXBK][SLOTS];   // 38.4 KB
    __shared__ int  lcnt[MAXBK];           // 1.6 KB
    int tid = threadIdx.x;
    for (int i = tid; i < MAXBK; i += blockDim.x) lcnt[i] = 0;
    __syncthreads();
    int chunk = (E + gridDim.x - 1) / gridDim.x;
    int c0 = blockIdx.x * chunk;
    int c1 = min(E, c0 + chunk);
    float gb = gate_b[0];
    for (int base = c0; base < c1; base += (int)blockDim.x) {
        int i = base + tid;
        if (i < c1) {
            int t = edst[i];
            int s = esrc[i];
            float g  = fast_tanh(gd[t] + gs[s] + gb);
            float ev = g * d[t] * d[s];
            int b = t >> BKSH;
            int2 rec = make_int2((s << BKSH) | (t & (BKN - 1)), __float_as_int(ev));
            int pos = atomicAdd(&lcnt[b], 1);
            if (pos < SLOTS) stage[b][pos] = rec;
            else pairs[atomicAdd(&gcur[b], 1)] = rec;   // rare overflow
        }
        __syncthreads();
        // flush any bucket with >=8 staged records as one 64B group
        for (int b = tid; b < nbk; b += (int)blockDim.x) {
            int p = min(lcnt[b], SLOTS);
            if (p >= 8) {
                int gp = atomicAdd(&gcur[b], 8);
                int2* dst = &pairs[gp];
                #pragma unroll
                for (int k = 0; k < 8; ++k) dst[k] = stage[b][k];
                int rem = p - 8;
                #pragma unroll
                for (int k = 0; k < SLOTS - 8; ++k)
                    if (k < rem) stage[b][k] = stage[b][8 + k];
                lcnt[b] = rem;
            }
        }
        __syncthreads();
    }
    // drain stragglers (partial lines, small)
    for (int b = tid; b < nbk; b += (int)blockDim.x) {
        int p = min(lcnt[b], SLOTS);
        if (p > 0) {
            int gp = atomicAdd(&gcur[b], p);
            for (int k = 0; k < p; ++k) pairs[gp + k] = stage[b][k];
        }
    }
}

// ---------- gather: one block per (bucket, dim-half); LDS z-tile, ds_add ----------
__global__ void fa_gather_bk(const __hip_bfloat16* __restrict__ hb,
                             const int* __restrict__ offbk, const int* __restrict__ cntbk,
                             const int2* __restrict__ pairs,
                             float* __restrict__ z, int N) {
    __shared__ float zt[BKN * 32];         // 32 KB
    int b      = blockIdx.x;
    int dimoff = blockIdx.y << 5;
    int tid    = threadIdx.x;
    for (int i = tid; i < BKN * 32; i += blockDim.x) zt[i] = 0.f;
    __syncthreads();
    int start = offbk[b];
    int c     = cntbk[b];
    int end   = start + c;
    int w    = tid >> 6;
    int lane = tid & 63;
    int half = lane >> 5;      // lanes 0-31 -> rec r, lanes 32-63 -> rec r+1
    int l32  = lane & 31;
    for (int r0 = start + (w << 1) + half; r0 < end; r0 += 32) {
        #pragma unroll
        for (int u = 0; u < 2; ++u) {
            int r = r0 + u * 16;
            if (r < end) {
                int2 rec = pairs[r];
                int src  = rec.x >> BKSH;
                int ldst = rec.x & (BKN - 1);
                float e  = __int_as_float(rec.y);
                float hv = __bfloat162float(hb[(size_t)src * DIM + dimoff + l32]);
                atomicAdd(&zt[(ldst << 5) + l32], hv * e);
            }
        }
    }
    __syncthreads();
    int n0 = b << BKSH;
    int nn = min(BKN, N - n0);
    int nq = nn * 8;                        // float4 count (32 dims = 8 float4/row)
    const float4* t4 = (const float4*)zt;
    for (int i = tid; i < nq; i += blockDim.x) {
        int row = i >> 3;
        int q   = i & 7;
        *(float4*)&z[(size_t)(n0 + row) * DIM + dimoff + (q << 2)] = t4[i];
    }
}

// ---------- fallback: atomic scatter ----------
__global__ void fa_edge_scatter_atomic(const float* __restrict__ h,
                                       const float* __restrict__ d,
                                       const float* __restrict__ gd,
                                       const float* __restrict__ gs,
                                       const int* __restrict__ esrc,
                                       const int* __restrict__ edst,
                                       const float* __restrict__ gate_b,
                                       float* __restrict__ z, int E) {
    int gid  = blockIdx.x * blockDim.x + threadIdx.x;
    int edge = gid >> 6;
    int lane = threadIdx.x & 63;
    if (edge >= E) return;
    int s = esrc[edge];
    int t = edst[edge];
    float g  = fast_tanh(gd[t] + gs[s] + gate_b[0]);
    float ev = g * d[t] * d[s];
    atomicAdd(&z[(size_t)t * DIM + lane], h[(size_t)s * DIM + lane] * ev);
}

extern "C" void kernel_launch(void* const* d_in, const int* in_sizes, int n_in,
                              void* d_out, int out_size, void* d_ws, size_t ws_size,
                              hipStream_t stream) {
    const float* h      = (const float*)d_in[0];
    const float* d      = (const float*)d_in[1];
    const float* gate_W = (const float*)d_in[2];
    const float* gate_b = (const float*)d_in[3];
    const int*   esrc   = (const int*)d_in[4];
    const int*   edst   = (const int*)d_in[5];
    float*       z      = (float*)d_out;

    int N = in_sizes[1];
    int E = in_sizes[4];
    int nbk = (N + BKN - 1) >> BKSH;

    // workspace layout
    char* w = (char*)d_ws;
    float* gd    = (float*)w;          w += (size_t)N * 4;
    float* gs    = (float*)w;          w += (size_t)N * 4;
    int*   cntbk = (int*)w;            w += (size_t)MAXBK * 4;
    int*   offbk = (int*)w;            w += (size_t)MAXBK * 4;
    int*   gcur  = (int*)w;            w += (size_t)MAXBK * 4;
    w = (char*)(((uintptr_t)w + 63) & ~(uintptr_t)63);
    int2* pairs  = (int2*)w;           w += ((size_t)E + MAXBK * 8) * 8;
    __hip_bfloat16* hb = (__hip_bfloat16*)w;
    w += (size_t)N * DIM * 2;
    size_t required = (size_t)(w - (char*)d_ws);
    size_t atomic_required = (size_t)N * 8;

    bool use_bucket = (ws_size >= required) && (N <= MAXBK * BKN) && (nbk <= 512);

    fa_node_gates<<<(N + 3) / 4, 256, 0, stream>>>(h, gate_W, gd, gs,
                                                   use_bucket ? hb : (__hip_bfloat16*)nullptr, N);

    if (use_bucket) {
        hipMemsetAsync(cntbk, 0, (size_t)MAXBK * 4, stream);
        fa_hist_bk<<<1024, 256, 0, stream>>>(edst, cntbk, E);
        fa_scan_bk<<<1, 512, 0, stream>>>(cntbk, offbk, gcur, nbk);
        fa_scatter_bk<<<512, 512, 0, stream>>>(gd, gs, d, esrc, edst, gate_b,
                                               gcur, pairs, E, nbk);
        dim3 gg(nbk, 2);
        fa_gather_bk<<<gg, 512, 0, stream>>>(hb, offbk, cntbk, pairs, z, N);
    } else if (ws_size >= atomic_required) {
        hipMemsetAsync(z, 0, (size_t)out_size * sizeof(float), stream);
        fa_edge_scatter_atomic<<<(E + 3) / 4, 256, 0, stream>>>(h, d, gd, gs, esrc,
                                                                edst, gate_b, z, E);
    }
}

// Round 5
// 1509.004 us; speedup vs baseline: 1.0028x; 1.0028x over previous
//
#include <hip/hip_runtime.h>
#include <hip/hip_bf16.h>

#define DIM 64
#define BKN 256              // nodes per bucket
#define BKSH 8               // log2(BKN)
#define MAXBK 400            // supports N <= 102400
#define SORTB 512            // blocks for the two-pass sort
#define SORTT 512            // threads per sort block

__device__ inline float fast_tanh(float x) {
    float e = __expf(2.0f * x);
    return 1.0f - 2.0f / (e + 1.0f);
}

// ---------- gates: per-node dot products + bf16 copy of h ----------
__global__ void fa_node_gates(const float* __restrict__ h,
                              const float* __restrict__ gate_W,
                              float* __restrict__ gd,
                              float* __restrict__ gs,
                              __hip_bfloat16* __restrict__ hb,   // may be null
                              int N) {
    int gid  = blockIdx.x * blockDim.x + threadIdx.x;
    int node = gid >> 6;
    int lane = threadIdx.x & 63;
    if (node >= N) return;
    float x = h[(size_t)node * DIM + lane];
    if (hb) hb[(size_t)node * DIM + lane] = __float2bfloat16(x);
    float a = x * gate_W[lane];
    float b = x * gate_W[DIM + lane];
    #pragma unroll
    for (int off = 32; off >= 1; off >>= 1) {
        a += __shfl_xor(a, off, 64);
        b += __shfl_xor(b, off, 64);
    }
    if (lane == 0) {
        gd[node] = a;
        gs[node] = b;
    }
}

// ---------- pass 1: per-block bucket histogram ----------
// cnt layout: cnt[blk * MAXBK + bk]
__global__ void fa_sort_hist(const int* __restrict__ edst, int* __restrict__ cnt, int E) {
    __shared__ int lh[MAXBK];
    int tid = threadIdx.x;
    for (int i = tid; i < MAXBK; i += blockDim.x) lh[i] = 0;
    __syncthreads();
    int chunk = (E + gridDim.x - 1) / gridDim.x;
    int c0 = blockIdx.x * chunk;
    int c1 = min(E, c0 + chunk);
    for (int i = c0 + tid; i < c1; i += blockDim.x)
        atomicAdd(&lh[edst[i] >> BKSH], 1);
    __syncthreads();
    for (int i = tid; i < MAXBK; i += blockDim.x)
        cnt[blockIdx.x * MAXBK + i] = lh[i];
}

// ---------- scan A: per-bucket exclusive prefix over blocks; bucket totals ----------
// one block per bucket; 512 threads (== SORTB)
__global__ void fa_sort_scanA(int* __restrict__ cnt, int* __restrict__ bktot) {
    __shared__ int sc[SORTB];
    int bk  = blockIdx.x;
    int tid = threadIdx.x;
    int v = cnt[tid * MAXBK + bk];
    sc[tid] = v;
    __syncthreads();
    for (int dd = 1; dd < SORTB; dd <<= 1) {
        int t = (tid >= dd) ? sc[tid - dd] : 0;
        __syncthreads();
        sc[tid] += t;
        __syncthreads();
    }
    cnt[tid * MAXBK + bk] = sc[tid] - v;         // exclusive block prefix
    if (tid == SORTB - 1) bktot[bk] = sc[tid];   // bucket total
}

// ---------- scan B: exclusive scan of bucket totals ----------
__global__ void fa_sort_scanB(const int* __restrict__ bktot, int* __restrict__ bkoff, int nbk) {
    __shared__ int sc[512];
    int tid = threadIdx.x;
    int v = (tid < nbk) ? bktot[tid] : 0;
    sc[tid] = v;
    __syncthreads();
    for (int dd = 1; dd < 512; dd <<= 1) {
        int t = (tid >= dd) ? sc[tid - dd] : 0;
        __syncthreads();
        sc[tid] += t;
        __syncthreads();
    }
    if (tid < nbk) bkoff[tid] = sc[tid] - v;
}

// ---------- pass 2: compute gate, place record in bucket region (no global atomics) ----------
__global__ void fa_sort_place(const float* __restrict__ gd, const float* __restrict__ gs,
                              const float* __restrict__ d,
                              const int* __restrict__ esrc, const int* __restrict__ edst,
                              const float* __restrict__ gate_b,
                              const int* __restrict__ cnt, const int* __restrict__ bkoff,
                              int2* __restrict__ pairs, int E, int nbk) {
    __shared__ int lcur[MAXBK];
    int tid = threadIdx.x;
    for (int i = tid; i < nbk; i += blockDim.x)
        lcur[i] = bkoff[i] + cnt[blockIdx.x * MAXBK + i];
    __syncthreads();
    int chunk = (E + gridDim.x - 1) / gridDim.x;
    int c0 = blockIdx.x * chunk;
    int c1 = min(E, c0 + chunk);
    float gb = gate_b[0];
    for (int i = c0 + tid; i < c1; i += blockDim.x) {
        int t = edst[i];
        int s = esrc[i];
        float g  = fast_tanh(gd[t] + gs[s] + gb);
        float ev = g * d[t] * d[s];
        int bk = t >> BKSH;
        int pos = atomicAdd(&lcur[bk], 1);       // LDS atomic
        pairs[pos] = make_int2((s << BKSH) | (t & (BKN - 1)), __float_as_int(ev));
    }
}

// ---------- gather: block per (bucket, dim-half); batched pairs + 8-deep MLP ----------
__global__ void fa_gather2(const __hip_bfloat16* __restrict__ hb,
                           const int* __restrict__ bkoff, const int* __restrict__ bktot,
                           const int2* __restrict__ pairs,
                           float* __restrict__ z, int N) {
    __shared__ float zt[BKN * 32];               // 32 KB
    int bk     = blockIdx.x;
    int dimoff = blockIdx.y << 5;
    int tid    = threadIdx.x;
    for (int i = tid; i < BKN * 32; i += blockDim.x) zt[i] = 0.f;
    __syncthreads();
    int start = bkoff[bk];
    int c     = bktot[bk];
    int end   = start + c;
    int cl   = tid >> 5;        // cluster 0..15
    int l32  = tid & 31;
    int cbase = tid & 32;       // cluster base lane within the wave (0 or 32)
    const int NCL = 16;         // 512 threads / 32
    for (int r0 = start + cl * 32; r0 < end; r0 += NCL * 32) {
        int r = r0 + l32;
        int2 myp = make_int2(0, 0);              // e = 0 for out-of-range
        if (r < end) myp = pairs[r];
        #pragma unroll
        for (int g = 0; g < 4; ++g) {
            float hv[8]; float ev[8]; int ld[8];
            #pragma unroll
            for (int j = 0; j < 8; ++j) {
                int lane = cbase + g * 8 + j;
                int px = __shfl(myp.x, lane, 64);
                int py = __shfl(myp.y, lane, 64);
                ld[j] = px & (BKN - 1);
                ev[j] = __int_as_float(py);
                int src = px >> BKSH;
                hv[j] = __bfloat162float(hb[(size_t)src * DIM + dimoff + l32]);
            }
            #pragma unroll
            for (int j = 0; j < 8; ++j)
                atomicAdd(&zt[(ld[j] << 5) + l32], hv[j] * ev[j]);
        }
    }
    __syncthreads();
    int n0 = bk << BKSH;
    int nn = min(BKN, N - n0);
    int nq = nn * 8;                              // 8 float4 per 32-dim row
    const float4* t4 = (const float4*)zt;
    for (int i = tid; i < nq; i += blockDim.x) {
        int row = i >> 3;
        int q   = i & 7;
        *(float4*)&z[(size_t)(n0 + row) * DIM + dimoff + (q << 2)] = t4[i];
    }
}

// ---------- fallback: atomic scatter ----------
__global__ void fa_edge_scatter_atomic(const float* __restrict__ h,
                                       const float* __restrict__ d,
                                       const float* __restrict__ gd,
                                       const float* __restrict__ gs,
                                       const int* __restrict__ esrc,
                                       const int* __restrict__ edst,
                                       const float* __restrict__ gate_b,
                                       float* __restrict__ z, int E) {
    int gid  = blockIdx.x * blockDim.x + threadIdx.x;
    int edge = gid >> 6;
    int lane = threadIdx.x & 63;
    if (edge >= E) return;
    int s = esrc[edge];
    int t = edst[edge];
    float g  = fast_tanh(gd[t] + gs[s] + gate_b[0]);
    float ev = g * d[t] * d[s];
    atomicAdd(&z[(size_t)t * DIM + lane], h[(size_t)s * DIM + lane] * ev);
}

extern "C" void kernel_launch(void* const* d_in, const int* in_sizes, int n_in,
                              void* d_out, int out_size, void* d_ws, size_t ws_size,
                              hipStream_t stream) {
    const float* h      = (const float*)d_in[0];
    const float* d      = (const float*)d_in[1];
    const float* gate_W = (const float*)d_in[2];
    const float* gate_b = (const float*)d_in[3];
    const int*   esrc   = (const int*)d_in[4];
    const int*   edst   = (const int*)d_in[5];
    float*       z      = (float*)d_out;

    int N = in_sizes[1];
    int E = in_sizes[4];
    int nbk = (N + BKN - 1) >> BKSH;

    // workspace layout
    char* w = (char*)d_ws;
    float* gd    = (float*)w;          w += (size_t)N * 4;
    float* gs    = (float*)w;          w += (size_t)N * 4;
    int*   bktot = (int*)w;            w += (size_t)MAXBK * 4;
    int*   bkoff = (int*)w;            w += (size_t)MAXBK * 4;
    int*   cnt   = (int*)w;            w += (size_t)SORTB * MAXBK * 4;   // 800 KB
    w = (char*)(((uintptr_t)w + 63) & ~(uintptr_t)63);
    int2* pairs  = (int2*)w;           w += ((size_t)E + 64) * 8;
    __hip_bfloat16* hb = (__hip_bfloat16*)w;
    w += (size_t)N * DIM * 2;
    size_t required = (size_t)(w - (char*)d_ws);
    size_t atomic_required = (size_t)N * 8;

    bool use_bucket = (ws_size >= required) && (N <= MAXBK * BKN) && (nbk <= MAXBK);

    fa_node_gates<<<(N + 3) / 4, 256, 0, stream>>>(h, gate_W, gd, gs,
                                                   use_bucket ? hb : (__hip_bfloat16*)nullptr, N);

    if (use_bucket) {
        fa_sort_hist<<<SORTB, SORTT, 0, stream>>>(edst, cnt, E);
        fa_sort_scanA<<<nbk, SORTB, 0, stream>>>(cnt, bktot);
        fa_sort_scanB<<<1, 512, 0, stream>>>(bktot, bkoff, nbk);
        fa_sort_place<<<SORTB, SORTT, 0, stream>>>(gd, gs, d, esrc, edst, gate_b,
                                                   cnt, bkoff, pairs, E, nbk);
        dim3 gg(nbk, 2);
        fa_gather2<<<gg, 512, 0, stream>>>(hb, bkoff, bktot, pairs, z, N);
    } else if (ws_size >= atomic_required) {
        hipMemsetAsync(z, 0, (size_t)out_size * sizeof(float), stream);
        fa_edge_scatter_atomic<<<(E + 3) / 4, 256, 0, stream>>>(h, d, gd, gs, esrc,
                                                                edst, gate_b, z, E);
    }
}

// Round 6
// 245.156 us; speedup vs baseline: 6.1727x; 6.1553x over previous
//
#include <hip/hip_runtime.h>
#include <hip/hip_bf16.h>

#define DIM 64
#define BKN 128              // nodes per bucket
#define BKSH 7               // log2(BKN)
#define MAXBK 800            // supports N <= 102400
#define SORTB 512            // blocks for the two-pass sort
#define SORTT 512            // threads per sort block
#define CAP 7500             // stage-2 LDS record capacity (60 KB); mean is ~4096

__device__ inline float fast_tanh(float x) {
    float e = __expf(2.0f * x);
    return 1.0f - 2.0f / (e + 1.0f);
}

// ---------- gates: per-node dot products + bf16 copy of h ----------
__global__ void fa_node_gates(const float* __restrict__ h,
                              const float* __restrict__ gate_W,
                              float* __restrict__ gd,
                              float* __restrict__ gs,
                              __hip_bfloat16* __restrict__ hb,   // may be null
                              int N) {
    int gid  = blockIdx.x * blockDim.x + threadIdx.x;
    int node = gid >> 6;
    int lane = threadIdx.x & 63;
    if (node >= N) return;
    float x = h[(size_t)node * DIM + lane];
    if (hb) hb[(size_t)node * DIM + lane] = __float2bfloat16(x);
    float a = x * gate_W[lane];
    float b = x * gate_W[DIM + lane];
    #pragma unroll
    for (int off = 32; off >= 1; off >>= 1) {
        a += __shfl_xor(a, off, 64);
        b += __shfl_xor(b, off, 64);
    }
    if (lane == 0) {
        gd[node] = a;
        gs[node] = b;
    }
}

// ---------- pass 1: per-block bucket histogram (cnt[blk*MAXBK + bk]) ----------
__global__ void fa_sort_hist(const int* __restrict__ edst, int* __restrict__ cnt, int E) {
    __shared__ int lh[MAXBK];
    int tid = threadIdx.x;
    for (int i = tid; i < MAXBK; i += blockDim.x) lh[i] = 0;
    __syncthreads();
    int chunk = (E + gridDim.x - 1) / gridDim.x;
    int c0 = blockIdx.x * chunk;
    int c1 = min(E, c0 + chunk);
    for (int i = c0 + tid; i < c1; i += blockDim.x)
        atomicAdd(&lh[edst[i] >> BKSH], 1);
    __syncthreads();
    for (int i = tid; i < MAXBK; i += blockDim.x)
        cnt[blockIdx.x * MAXBK + i] = lh[i];
}

// ---------- scan A: per-bucket exclusive prefix over blocks; bucket totals ----------
__global__ void fa_sort_scanA(int* __restrict__ cnt, int* __restrict__ bktot) {
    __shared__ int sc[SORTB];
    int bk  = blockIdx.x;
    int tid = threadIdx.x;
    int v = cnt[tid * MAXBK + bk];
    sc[tid] = v;
    __syncthreads();
    for (int dd = 1; dd < SORTB; dd <<= 1) {
        int t = (tid >= dd) ? sc[tid - dd] : 0;
        __syncthreads();
        sc[tid] += t;
        __syncthreads();
    }
    cnt[tid * MAXBK + bk] = sc[tid] - v;
    if (tid == SORTB - 1) bktot[bk] = sc[tid];
}

// ---------- scan B: exclusive scan of bucket totals; off[N] = E sentinel ----------
__global__ void fa_sort_scanB(const int* __restrict__ bktot, int* __restrict__ bkoff,
                              int* __restrict__ off, int nbk, int E, int N) {
    __shared__ int sc[1024];
    int tid = threadIdx.x;
    int v = (tid < nbk) ? bktot[tid] : 0;
    sc[tid] = v;
    __syncthreads();
    for (int dd = 1; dd < 1024; dd <<= 1) {
        int t = (tid >= dd) ? sc[tid - dd] : 0;
        __syncthreads();
        sc[tid] += t;
        __syncthreads();
    }
    if (tid < nbk) bkoff[tid] = sc[tid] - v;
    if (tid == 0) off[N] = E;
}

// ---------- pass 2: gate compute + place record in bucket region ----------
__global__ void fa_sort_place(const float* __restrict__ gd, const float* __restrict__ gs,
                              const float* __restrict__ d,
                              const int* __restrict__ esrc, const int* __restrict__ edst,
                              const float* __restrict__ gate_b,
                              const int* __restrict__ cnt, const int* __restrict__ bkoff,
                              int2* __restrict__ pairs, int E, int nbk) {
    __shared__ int lcur[MAXBK];
    int tid = threadIdx.x;
    for (int i = tid; i < nbk; i += blockDim.x)
        lcur[i] = bkoff[i] + cnt[blockIdx.x * MAXBK + i];
    __syncthreads();
    int chunk = (E + gridDim.x - 1) / gridDim.x;
    int c0 = blockIdx.x * chunk;
    int c1 = min(E, c0 + chunk);
    float gb = gate_b[0];
    for (int i = c0 + tid; i < c1; i += blockDim.x) {
        int t = edst[i];
        int s = esrc[i];
        float g  = fast_tanh(gd[t] + gs[s] + gb);
        float ev = g * d[t] * d[s];
        int bk = t >> BKSH;
        int pos = atomicAdd(&lcur[bk], 1);       // LDS atomic
        pairs[pos] = make_int2((s << BKSH) | (t & (BKN - 1)), __float_as_int(ev));
    }
}

// ---------- stage 2: in-LDS per-node counting sort within each bucket ----------
__global__ void fa_stage2(int2* __restrict__ pairs,
                          const int* __restrict__ bkoff, const int* __restrict__ bktot,
                          int* __restrict__ off, int* __restrict__ flags, int N) {
    __shared__ int2 buf[CAP];                    // 60 KB
    __shared__ int hist[BKN];
    __shared__ int sc[BKN];
    __shared__ int cur[BKN];
    int bk  = blockIdx.x;
    int tid = threadIdx.x;                       // 256 threads
    int s0  = bkoff[bk];
    int c   = bktot[bk];
    if (c > CAP) {                               // adversarial skew: leave unsorted
        if (tid == 0) {
            flags[bk] = 1;
            int n0 = bk << BKSH;
            if (n0 < N) off[n0] = s0;            // keep boundary offsets valid
        }
        return;
    }
    if (tid < BKN) hist[tid] = 0;
    __syncthreads();
    for (int i = tid; i < c; i += blockDim.x) {
        int2 r = pairs[s0 + i];
        buf[i] = r;
        atomicAdd(&hist[r.x & (BKN - 1)], 1);
    }
    __syncthreads();
    int v = (tid < BKN) ? hist[tid] : 0;
    if (tid < BKN) sc[tid] = v;
    __syncthreads();
    for (int dd = 1; dd < BKN; dd <<= 1) {
        int t = (tid < BKN && tid >= dd) ? sc[tid - dd] : 0;
        __syncthreads();
        if (tid < BKN) sc[tid] += t;
        __syncthreads();
    }
    if (tid < BKN) {
        int excl = sc[tid] - v;
        cur[tid] = excl;
        int node = (bk << BKSH) + tid;
        if (node < N) off[node] = s0 + excl;
    }
    __syncthreads();
    for (int i = tid; i < c; i += blockDim.x) {
        int2 r = buf[i];
        int p = atomicAdd(&cur[r.x & (BKN - 1)], 1);   // LDS atomic
        pairs[s0 + p] = r;
    }
}

// ---------- gather: wave per node, register accumulation (R2 structure) ----------
__global__ void fa_gather3(const __hip_bfloat16* __restrict__ hb,
                           const int* __restrict__ off,
                           const int* __restrict__ bkoff, const int* __restrict__ bktot,
                           const int* __restrict__ flags,
                           const int2* __restrict__ pairs,
                           float* __restrict__ z, int N) {
    int gid  = blockIdx.x * blockDim.x + threadIdx.x;
    int node = gid >> 6;
    int lane = threadIdx.x & 63;
    if (node >= N) return;
    int bk = node >> BKSH;
    float a0 = 0.f, a1 = 0.f, a2 = 0.f, a3 = 0.f;
    if (!flags[bk]) {
        int j   = off[node];
        int end = off[node + 1];
        for (; j + 4 <= end; j += 4) {
            int2 p0 = pairs[j];
            int2 p1 = pairs[j + 1];
            int2 p2 = pairs[j + 2];
            int2 p3 = pairs[j + 3];
            a0 += __bfloat162float(hb[((size_t)(p0.x >> BKSH)) * DIM + lane]) * __int_as_float(p0.y);
            a1 += __bfloat162float(hb[((size_t)(p1.x >> BKSH)) * DIM + lane]) * __int_as_float(p1.y);
            a2 += __bfloat162float(hb[((size_t)(p2.x >> BKSH)) * DIM + lane]) * __int_as_float(p2.y);
            a3 += __bfloat162float(hb[((size_t)(p3.x >> BKSH)) * DIM + lane]) * __int_as_float(p3.y);
        }
        for (; j < end; ++j) {
            int2 p = pairs[j];
            a0 += __bfloat162float(hb[((size_t)(p.x >> BKSH)) * DIM + lane]) * __int_as_float(p.y);
        }
    } else {
        // correct slow path for oversized (unsorted) buckets
        int s0 = bkoff[bk], end = s0 + bktot[bk];
        int want = node & (BKN - 1);
        for (int j = s0; j < end; ++j) {
            int2 p = pairs[j];
            if ((p.x & (BKN - 1)) == want)
                a0 += __bfloat162float(hb[((size_t)(p.x >> BKSH)) * DIM + lane]) * __int_as_float(p.y);
        }
    }
    z[(size_t)node * DIM + lane] = a0 + a1 + a2 + a3;
}

// ---------- fallback: atomic scatter ----------
__global__ void fa_edge_scatter_atomic(const float* __restrict__ h,
                                       const float* __restrict__ d,
                                       const float* __restrict__ gd,
                                       const float* __restrict__ gs,
                                       const int* __restrict__ esrc,
                                       const int* __restrict__ edst,
                                       const float* __restrict__ gate_b,
                                       float* __restrict__ z, int E) {
    int gid  = blockIdx.x * blockDim.x + threadIdx.x;
    int edge = gid >> 6;
    int lane = threadIdx.x & 63;
    if (edge >= E) return;
    int s = esrc[edge];
    int t = edst[edge];
    float g  = fast_tanh(gd[t] + gs[s] + gate_b[0]);
    float ev = g * d[t] * d[s];
    atomicAdd(&z[(size_t)t * DIM + lane], h[(size_t)s * DIM + lane] * ev);
}

extern "C" void kernel_launch(void* const* d_in, const int* in_sizes, int n_in,
                              void* d_out, int out_size, void* d_ws, size_t ws_size,
                              hipStream_t stream) {
    const float* h      = (const float*)d_in[0];
    const float* d      = (const float*)d_in[1];
    const float* gate_W = (const float*)d_in[2];
    const float* gate_b = (const float*)d_in[3];
    const int*   esrc   = (const int*)d_in[4];
    const int*   edst   = (const int*)d_in[5];
    float*       z      = (float*)d_out;

    int N = in_sizes[1];
    int E = in_sizes[4];
    int nbk = (N + BKN - 1) >> BKSH;

    // workspace layout
    char* w = (char*)d_ws;
    float* gd    = (float*)w;          w += (size_t)N * 4;
    float* gs    = (float*)w;          w += (size_t)N * 4;
    int*   bktot = (int*)w;            w += (size_t)MAXBK * 4;
    int*   bkoff = (int*)w;            w += (size_t)MAXBK * 4;
    int*   flags = (int*)w;            w += (size_t)MAXBK * 4;
    int*   cnt   = (int*)w;            w += (size_t)SORTB * MAXBK * 4;  // 1.64 MB
    int*   off   = (int*)w;            w += (size_t)(N + 1) * 4;
    w = (char*)(((uintptr_t)w + 63) & ~(uintptr_t)63);
    int2* pairs  = (int2*)w;           w += ((size_t)E + 64) * 8;
    __hip_bfloat16* hb = (__hip_bfloat16*)w;
    w += (size_t)N * DIM * 2;
    size_t required = (size_t)(w - (char*)d_ws);
    size_t atomic_required = (size_t)N * 8;

    bool use_sort = (ws_size >= required) && (nbk <= MAXBK);

    fa_node_gates<<<(N + 3) / 4, 256, 0, stream>>>(h, gate_W, gd, gs,
                                                   use_sort ? hb : (__hip_bfloat16*)nullptr, N);

    if (use_sort) {
        hipMemsetAsync(flags, 0, (size_t)MAXBK * 4, stream);
        fa_sort_hist<<<SORTB, SORTT, 0, stream>>>(edst, cnt, E);
        fa_sort_scanA<<<nbk, SORTB, 0, stream>>>(cnt, bktot);
        fa_sort_scanB<<<1, 1024, 0, stream>>>(bktot, bkoff, off, nbk, E, N);
        fa_sort_place<<<SORTB, SORTT, 0, stream>>>(gd, gs, d, esrc, edst, gate_b,
                                                   cnt, bkoff, pairs, E, nbk);
        fa_stage2<<<nbk, 256, 0, stream>>>(pairs, bkoff, bktot, off, flags, N);
        fa_gather3<<<(N * 64 + 255) / 256, 256, 0, stream>>>(hb, off, bkoff, bktot,
                                                             flags, pairs, z, N);
    } else if (ws_size >= atomic_required) {
        hipMemsetAsync(z, 0, (size_t)out_size * sizeof(float), stream);
        fa_edge_scatter_atomic<<<(E + 3) / 4, 256, 0, stream>>>(h, d, gd, gs, esrc,
                                                                edst, gate_b, z, E);
    }
}